// Round 1
// baseline (35.509 us; speedup 1.0000x reference)
//
#include <hip/hip_runtime.h>
#include <math.h>

#define RESN 2048
#define RES_SHIFT 11
#define TEXW 1024

__global__ __launch_bounds__(256) void egg_render(
    const float* __restrict__ tex,
    const float* __restrict__ nmap,
    float* __restrict__ out)
{
    int p = blockIdx.x * 256 + threadIdx.x;
    if (p >= RESN * RESN) return;
    int i = p & (RESN - 1);
    int j = p >> RES_SHIFT;
    float* o = out + (size_t)p * 3u;

    const float invres = 1.0f / (float)RESN;
    // bit-exact vs numpy: no fma contraction allowed on the inside-test path
    float nx = __fmul_rn(__fsub_rn(__fmul_rn((float)i, invres), 0.5f), 2.0f) / 0.85f;
    float ny = __fmul_rn(__fsub_rn(0.5f, __fmul_rn((float)j, invres)), 2.0f) / 0.85f;

    float rsq = __fadd_rn(__fmul_rn(nx, nx), __fmul_rn(ny, ny));
    if (!(rsq <= 1.0f)) {
        o[0] = 0.0f; o[1] = 0.0f; o[2] = 0.0f;
        return;
    }

    float z = sqrtf(fmaxf(1.0f - rsq, 0.0f));
    float egg = 1.0f - 0.25f * ny;
    // reference's "safe" guard |egg|>0.01 is always true inside the disc
    // (ny in [-1,1] -> egg in [0.75,1.25])
    float ie = 1.0f / egg;
    float xe = nx * ie;
    float ze = z * ie;

    float phi = acosf(fminf(fmaxf(ny, -1.0f), 1.0f));
    float theta = atan2f(ze, xe);
    float u = theta * 0.15915494309189535f + 0.5f;  // 1/(2pi)
    u -= floorf(u);
    float v = phi * 0.3183098861837907f;            // 1/pi
    v -= floorf(v);

    // bilinear setup (wrap)
    float xx = u * (float)TEXW - 0.5f;
    float yy = v * (float)TEXW - 0.5f;
    float xf = floorf(xx), yf = floorf(yy);
    float fx = xx - xf, fy = yy - yf;
    int x0 = (int)xf & (TEXW - 1);
    int y0 = (int)yf & (TEXW - 1);
    int x1 = (x0 + 1) & (TEXW - 1);
    int y1 = (y0 + 1) & (TEXW - 1);
    float w00 = (1.0f - fx) * (1.0f - fy);
    float w01 = fx * (1.0f - fy);
    float w10 = (1.0f - fx) * fy;
    float w11 = fx * fy;
    int i00 = (y0 * TEXW + x0) * 3;
    int i01 = (y0 * TEXW + x1) * 3;
    int i10 = (y1 * TEXW + x0) * 3;
    int i11 = (y1 * TEXW + x1) * 3;

    float ar = tex[i00+0]*w00 + tex[i01+0]*w01 + tex[i10+0]*w10 + tex[i11+0]*w11;
    float ag = tex[i00+1]*w00 + tex[i01+1]*w01 + tex[i10+1]*w10 + tex[i11+1]*w11;
    float ab = tex[i00+2]*w00 + tex[i01+2]*w01 + tex[i10+2]*w10 + tex[i11+2]*w11;

    float tnx = (nmap[i00+0]*w00 + nmap[i01+0]*w01 + nmap[i10+0]*w10 + nmap[i11+0]*w11) * 2.0f - 1.0f;
    float tny = (nmap[i00+1]*w00 + nmap[i01+1]*w01 + nmap[i10+1]*w10 + nmap[i11+1]*w11) * 2.0f - 1.0f;
    float tnz = (nmap[i00+2]*w00 + nmap[i01+2]*w01 + nmap[i10+2]*w10 + nmap[i11+2]*w11) * 2.0f - 1.0f;

    // analytical egg normal
    float snx = nx * egg, sny = ny, snz = z * egg;
    float sl = sqrtf(snx*snx + sny*sny + snz*snz);
    float isl = 1.0f / fmaxf(sl, 1e-6f);
    float bnx = snx * isl, bny = sny * isl, bnz = snz * isl;

    // Gram-Schmidt TBN
    bool use_right = fabsf(bny) > 0.99f;
    float rx = use_right ? 1.0f : 0.0f;
    float ry = use_right ? 0.0f : 1.0f;
    float d  = use_right ? bnx : bny;   // dot(ref, n)
    float tx = rx - d * bnx;
    float ty = ry - d * bny;
    float tz = -d * bnz;
    float tl = sqrtf(tx*tx + ty*ty + tz*tz);
    float itl = 1.0f / fmaxf(tl, 1e-6f);
    tx *= itl; ty *= itl; tz *= itl;
    float bxx = bny * tz - bnz * ty;
    float bxy = bnz * tx - bnx * tz;
    float bxz = bnx * ty - bny * tx;

    // perturbed normal; BUMP_STRENGTH = 1.0 -> nrm = normalize(world_n)
    float wx = tnx * tx + tny * bxx + tnz * bnx;
    float wy = tnx * ty + tny * bxy + tnz * bny;
    float wz = tnx * tz + tny * bxz + tnz * bnz;
    float wl = sqrtf(wx*wx + wy*wy + wz*wz);
    float iwl = 1.0f / fmaxf(wl, 1e-6f);
    wx *= iwl; wy *= iwl; wz *= iwl;

    // lighting constants (constant-folded in f32 semantics, matching numpy)
    float Lx = 0.5f, Ly = 0.7f, Lz = 1.0f;
    float ll = sqrtf(Lx*Lx + Ly*Ly + Lz*Lz);
    Lx /= ll; Ly /= ll; Lz /= ll;
    float Hx = Lx, Hy = Ly, Hz = Lz + 1.0f;
    float hl = sqrtf(Hx*Hx + Hy*Hy + Hz*Hz);
    Hx /= hl; Hy /= hl; Hz /= hl;

    float ndotl = fmaxf(wx*Lx + wy*Ly + wz*Lz, 0.0f);
    float ndoth = fmaxf(wx*Hx + wy*Hy + wz*Hz, 0.0f);
    float s2 = ndoth * ndoth, s4 = s2 * s2, s8 = s4 * s4, s16 = s8 * s8;
    float spec = s16 * s16;                       // ndoth^32
    float ndotv = fmaxf(wz, 0.0f);
    float t1 = 1.0f - ndotv;
    float t2 = t1 * t1, t4 = t2 * t2;
    float fres = 0.04f + 0.96f * (t4 * t1);       // Schlick, F0=0.04
    float ka = 0.1f + ndotl;
    float add = spec * fres;

    o[0] = fminf(fmaxf(ar * ka + add, 0.0f), 1.0f);
    o[1] = fminf(fmaxf(ag * ka + add, 0.0f), 1.0f);
    o[2] = fminf(fmaxf(ab * ka + add, 0.0f), 1.0f);
}

extern "C" void kernel_launch(void* const* d_in, const int* in_sizes, int n_in,
                              void* d_out, int out_size, void* d_ws, size_t ws_size,
                              hipStream_t stream) {
    const float* tex  = (const float*)d_in[0];
    const float* nmap = (const float*)d_in[1];
    float* out = (float*)d_out;
    int total = RESN * RESN;
    dim3 grid((total + 255) / 256), block(256);
    hipLaunchKernelGGL(egg_render, grid, block, 0, stream, tex, nmap, out);
}

// Round 3
// 28.061 us; speedup vs baseline: 1.2654x; 1.2654x over previous
//
#include <hip/hip_runtime.h>
#include <math.h>

#define RESN 2048
#define TEXW 1024

// atan2 for y >= 0, returns [0, pi]. Cephes-style: min/max ratio + pi/8
// reduction + 4-term odd minimax. Peak err ~2e-7 rad.
__device__ __forceinline__ float fatan2_pos(float y, float x) {
    float ax = fabsf(x);
    float mn = fminf(ax, y);
    float mx = fmaxf(ax, y);
    float r0 = __builtin_amdgcn_rcpf(mx);
    r0 = r0 * __builtin_fmaf(-mx, r0, 2.0f);        // 1 Newton step -> ~0.5 ulp
    float a = mn * r0;                               // in [0,1]
    bool red = a > 0.41421356f;
    float t = (a - 1.0f) * __builtin_amdgcn_rcpf(a + 1.0f);  // in [-0.4142, 0]
    float w = red ? t : a;                           // |w| <= 0.41421356
    float s = w * w;
    float p = __builtin_fmaf(s, 8.05374449538e-2f, -1.38776856032e-1f);
    p = __builtin_fmaf(s, p, 1.99777106478e-1f);
    p = __builtin_fmaf(s, p, -3.33329491539e-1f);
    float r = __builtin_fmaf(w * s, p, w);           // atan(w)
    r = red ? r + 0.78539816339f : r;                // + pi/4
    r = (y > ax) ? 1.57079632679f - r : r;
    r = (x < 0.0f) ? 3.14159265359f - r : r;
    return r;
}

__global__ __launch_bounds__(256) void egg_render(
    const float* __restrict__ tex,
    const float* __restrict__ nmap,
    float* __restrict__ out)
{
    int t = blockIdx.x * 256 + threadIdx.x;      // one thread = 4 consecutive pixels in a row
    int j = t >> 9;                              // row
    int i0 = (t & 511) << 2;                     // column base
    float4* ov = (float4*)(out + (size_t)t * 12u);

    const float invres = 1.0f / (float)RESN;
    // bit-exact vs numpy on the inside-test path: no fma contraction
    float ny = __fmul_rn(__fsub_rn(0.5f, __fmul_rn((float)j, invres)), 2.0f) / 0.85f;
    float nysq = __fmul_rn(ny, ny);

    if (!(nysq <= 1.0f)) {                       // whole row outside the disc
        ov[0] = make_float4(0.f, 0.f, 0.f, 0.f);
        ov[1] = make_float4(0.f, 0.f, 0.f, 0.f);
        ov[2] = make_float4(0.f, 0.f, 0.f, 0.f);
        return;
    }

    // ---- row-shared work (ny-only dependent) ----
    float egg = 1.0f - 0.25f * ny;               // in [0.75, 1.25] inside the disc
    // single-rounded 1-ny^2 (fma): no cancellation blow-up near poles
    float sphi = sqrtf(fmaxf(__builtin_fmaf(-ny, ny, 1.0f), 0.0f));
    float phi = fatan2_pos(sphi, ny);            // == acos(ny)
    float v = phi * 0.3183098861837907f;         // /pi
    v -= floorf(v);
    float yy = v * (float)TEXW - 0.5f;
    float yf = floorf(yy);
    float fy = yy - yf;
    float gy = 1.0f - fy;
    int y0 = (int)yf & (TEXW - 1);
    int y1 = (y0 + 1) & (TEXW - 1);
    int rb0 = y0 * TEXW;
    int rb1 = y1 * TEXW;

    // lighting constants (constant-folded at compile time in f32 semantics)
    float Lx = 0.5f, Ly = 0.7f, Lz = 1.0f;
    float ll = sqrtf(Lx * Lx + Ly * Ly + Lz * Lz);
    Lx /= ll; Ly /= ll; Lz /= ll;
    float Hx = Lx, Hy = Ly, Hz = Lz + 1.0f;
    float hl = sqrtf(Hx * Hx + Hy * Hy + Hz * Hz);
    Hx /= hl; Hy /= hl; Hz /= hl;

    float col[12];

    #pragma unroll
    for (int k = 0; k < 4; ++k) {
        float nx = __fmul_rn(__fsub_rn(__fmul_rn((float)(i0 + k), invres), 0.5f), 2.0f) / 0.85f;
        float rsq = __fadd_rn(__fmul_rn(nx, nx), nysq);
        if (!(rsq <= 1.0f)) {
            col[k * 3 + 0] = 0.0f; col[k * 3 + 1] = 0.0f; col[k * 3 + 2] = 0.0f;
            continue;
        }

        float z = sqrtf(fmaxf(__fsub_rn(1.0f, rsq), 0.0f));

        // atan2(z/egg, nx/egg) == atan2(z, nx): egg > 0 always inside the disc
        float theta = fatan2_pos(z, nx);
        float u = theta * 0.15915494309189535f + 0.5f;   // /(2pi)
        u -= floorf(u);

        // x-side bilinear (y-side shared)
        float xx = u * (float)TEXW - 0.5f;
        float xf = floorf(xx);
        float fx = xx - xf;
        float gx = 1.0f - fx;
        int x0 = (int)xf & (TEXW - 1);
        int x1 = (x0 + 1) & (TEXW - 1);
        float w00 = gx * gy, w01 = fx * gy, w10 = gx * fy, w11 = fx * fy;
        int i00 = (rb0 + x0) * 3;
        int i01 = (rb0 + x1) * 3;
        int i10 = (rb1 + x0) * 3;
        int i11 = (rb1 + x1) * 3;

        float ar = tex[i00+0]*w00 + tex[i01+0]*w01 + tex[i10+0]*w10 + tex[i11+0]*w11;
        float ag = tex[i00+1]*w00 + tex[i01+1]*w01 + tex[i10+1]*w10 + tex[i11+1]*w11;
        float ab = tex[i00+2]*w00 + tex[i01+2]*w01 + tex[i10+2]*w10 + tex[i11+2]*w11;

        float tnx = (nmap[i00+0]*w00 + nmap[i01+0]*w01 + nmap[i10+0]*w10 + nmap[i11+0]*w11) * 2.0f - 1.0f;
        float tny = (nmap[i00+1]*w00 + nmap[i01+1]*w01 + nmap[i10+1]*w10 + nmap[i11+1]*w11) * 2.0f - 1.0f;
        float tnz = (nmap[i00+2]*w00 + nmap[i01+2]*w01 + nmap[i10+2]*w10 + nmap[i11+2]*w11) * 2.0f - 1.0f;

        // analytical egg normal (|sn|^2 >= 0.5625 inside the disc)
        float snx = nx * egg, sny = ny, snz = z * egg;
        float sl2 = snx*snx + sny*sny + snz*snz;
        float isl = __builtin_amdgcn_rsqf(sl2);
        float bnx = snx * isl, bny = sny * isl, bnz = snz * isl;

        // Gram-Schmidt TBN (|t|^2 >= 0.0199)
        bool use_right = fabsf(bny) > 0.99f;
        float rx = use_right ? 1.0f : 0.0f;
        float ry = use_right ? 0.0f : 1.0f;
        float d  = use_right ? bnx : bny;
        float tx = rx - d * bnx;
        float ty = ry - d * bny;
        float tz = -d * bnz;
        float tl2 = tx*tx + ty*ty + tz*tz;
        float itl = __builtin_amdgcn_rsqf(tl2);
        tx *= itl; ty *= itl; tz *= itl;
        float bxx = bny * tz - bnz * ty;
        float bxy = bnz * tx - bnx * tz;
        float bxz = bnx * ty - bny * tx;

        // perturbed normal; BUMP_STRENGTH = 1 -> nrm = normalize(world_n)
        float wx = tnx * tx + tny * bxx + tnz * bnx;
        float wy = tnx * ty + tny * bxy + tnz * bny;
        float wz = tnx * tz + tny * bxz + tnz * bnz;
        float wl2 = wx*wx + wy*wy + wz*wz;
        float iwl = __builtin_amdgcn_rsqf(fmaxf(wl2, 1e-12f));
        wx *= iwl; wy *= iwl; wz *= iwl;

        float ndotl = fmaxf(wx * Lx + wy * Ly + wz * Lz, 0.0f);
        float ndoth = fmaxf(wx * Hx + wy * Hy + wz * Hz, 0.0f);
        float s2 = ndoth * ndoth, s4 = s2 * s2, s8 = s4 * s4, s16 = s8 * s8;
        float spec = s16 * s16;                   // ndoth^32
        float ndotv = fmaxf(wz, 0.0f);
        float t1 = 1.0f - ndotv;
        float t2 = t1 * t1, t4 = t2 * t2;
        float fres = 0.04f + 0.96f * (t4 * t1);   // Schlick, F0=0.04
        float ka = 0.1f + ndotl;
        float add = spec * fres;

        col[k * 3 + 0] = fminf(fmaxf(ar * ka + add, 0.0f), 1.0f);
        col[k * 3 + 1] = fminf(fmaxf(ag * ka + add, 0.0f), 1.0f);
        col[k * 3 + 2] = fminf(fmaxf(ab * ka + add, 0.0f), 1.0f);
    }

    ov[0] = make_float4(col[0], col[1],  col[2],  col[3]);
    ov[1] = make_float4(col[4], col[5],  col[6],  col[7]);
    ov[2] = make_float4(col[8], col[9],  col[10], col[11]);
}

extern "C" void kernel_launch(void* const* d_in, const int* in_sizes, int n_in,
                              void* d_out, int out_size, void* d_ws, size_t ws_size,
                              hipStream_t stream) {
    const float* tex  = (const float*)d_in[0];
    const float* nmap = (const float*)d_in[1];
    float* out = (float*)d_out;
    int total_threads = RESN * RESN / 4;          // 1,048,576
    dim3 grid(total_threads / 256), block(256);   // 4096 blocks
    hipLaunchKernelGGL(egg_render, grid, block, 0, stream, tex, nmap, out);
}